// Round 10
// baseline (739.598 us; speedup 1.0000x reference)
//
#include <hip/hip_runtime.h>
#include <hip/hip_bf16.h>
#include <cstdint>

typedef __bf16 bf16x8 __attribute__((ext_vector_type(8)));
typedef float  f32x4  __attribute__((ext_vector_type(4)));
typedef unsigned short u16;
typedef u16 u16x8 __attribute__((ext_vector_type(8)));

__device__ __forceinline__ u16 f2bf(float f) {
    union { float f; uint32_t u; } x{f};
    uint32_t u = x.u;
    return (u16)((u + 0x7fffu + ((u >> 16) & 1u)) >> 16);
}

__device__ __forceinline__ float gelu_f(float x) {
    return 0.5f * x * (1.0f + erff(x * 0.70710678118654752f));
}

// async global->LDS, 16B per lane; LDS dest is wave-uniform base + lane*16
__device__ __forceinline__ void gl_lds16(const void* g, void* l) {
    __builtin_amdgcn_global_load_lds(
        (__attribute__((address_space(1))) void*)(void*)g,
        (__attribute__((address_space(3))) void*)l, 16, 0, 0);
}

#define MFMA16(a, b, c) __builtin_amdgcn_mfma_f32_16x16x32_bf16((a), (b), (c), 0, 0, 0)
#define SB0 __builtin_amdgcn_sched_barrier(0)

// ---------------------------------------------------------------------------
// 128x128 GEMM, BK=64, 4 waves (2x2), single-buffered (measured best).
// LOC=1: linear grid remapped into 512-block chunks for L3 B-residency
// (decoder). SPLITK>1: grid.z splits K, partials to Cout + z*4096*N_.
// QS=1: multiply cols<768 by qs (pre-scales attention q by scale*log2e).
// ---------------------------------------------------------------------------
template<int EPI, int OUTF32, int LOC, int SPLITK, int QS>
__global__ __launch_bounds__(256, 2) void gemm_bf16(
    const u16* __restrict__ A, const u16* __restrict__ Bt,
    const float* __restrict__ bias, void* __restrict__ Cout,
    int N_, int K_, float qs)
{
    __shared__ u16 lA[128 * 64];
    __shared__ u16 lB[128 * 64];
    const int tid  = threadIdx.x;
    const int lane = tid & 63;
    const int wave = tid >> 6;
    const int wr = wave >> 1, wc = wave & 1;
    long row0, col0;
    if (LOC) {   // linear grid: chunk = 512 blocks = 32 rows x 16 cols, row fastest
        const int bid = blockIdx.x;
        const int chunk = bid >> 9, rem = bid & 511;
        row0 = (long)(rem & 31) * 128;
        col0 = (long)(chunk * 16 + (rem >> 5)) * 128;
    } else {
        row0 = (long)blockIdx.y * 128;
        col0 = (long)blockIdx.x * 128;
    }
    const int KS = K_ / SPLITK;
    const int kz = (SPLITK > 1) ? blockIdx.z * KS : 0;

    f32x4 acc[4][4];
#pragma unroll
    for (int i = 0; i < 4; ++i)
#pragma unroll
        for (int j = 0; j < 4; ++j)
#pragma unroll
            for (int t = 0; t < 4; ++t) acc[i][j][t] = 0.f;

    int sRow[4], sKb[4];
#pragma unroll
    for (int t = 0; t < 4; ++t) {
        int byteoff = (wave * 4 + t) * 1024 + lane * 16;
        int r = byteoff >> 7;
        sRow[t] = r;
        sKb[t]  = (byteoff & 127) ^ ((r & 7) << 4);
    }
    const int laneRC = lane & 15;
    const int laneK2 = (lane >> 4) * 16;

    for (int k0 = kz; k0 < kz + KS; k0 += 64) {
#pragma unroll
        for (int t = 0; t < 4; ++t) {
            const int cb = (wave * 4 + t) * 1024;
            gl_lds16(A  + (row0 + sRow[t]) * K_ + k0 + (sKb[t] >> 1), (char*)lA + cb);
            gl_lds16(Bt + (col0 + sRow[t]) * K_ + k0 + (sKb[t] >> 1), (char*)lB + cb);
        }
        __syncthreads();
#pragma unroll
        for (int kk = 0; kk < 2; ++kk) {
            bf16x8 af[4], bfr[4];
#pragma unroll
            for (int i = 0; i < 4; ++i) {
                int r = wr * 64 + i * 16 + laneRC;
                af[i] = *(const bf16x8*)((const char*)lA + r * 128 + ((kk * 64 + laneK2) ^ ((r & 7) << 4)));
            }
#pragma unroll
            for (int j = 0; j < 4; ++j) {
                int n = wc * 64 + j * 16 + laneRC;
                bfr[j] = *(const bf16x8*)((const char*)lB + n * 128 + ((kk * 64 + laneK2) ^ ((n & 7) << 4)));
            }
#pragma unroll
            for (int i = 0; i < 4; ++i)
#pragma unroll
                for (int j = 0; j < 4; ++j)
                    acc[i][j] = MFMA16(af[i], bfr[j], acc[i][j]);
        }
        __syncthreads();
    }

    float* outF = (float*)Cout + (SPLITK > 1 ? (long)blockIdx.z * 4096 * N_ : 0);
    const float qmul = (QS && col0 < 768) ? qs : 1.0f;
#pragma unroll
    for (int j = 0; j < 4; ++j) {
        const long cidx = col0 + wc * 64 + j * 16 + laneRC;
        const float bvv = (SPLITK == 1 || blockIdx.z == 0) ? bias[cidx] : 0.f;
#pragma unroll
        for (int i = 0; i < 4; ++i) {
            const long rbase = row0 + wr * 64 + i * 16 + ((lane >> 4) << 2);
#pragma unroll
            for (int t = 0; t < 4; ++t) {
                float v = acc[i][j][t] + bvv;
                if (QS) v *= qmul;
                if (EPI) v = gelu_f(v);
                const long off = (rbase + t) * N_ + cidx;
                if (OUTF32) outF[off] = v;
                else        ((u16*)Cout)[off] = f2bf(v);
            }
        }
    }
}

// ---------------------------------------------------------------------------
// 64x64 GEMM, BK=64, 4 waves (2x2, wave-tile 32x32), 16 KiB LDS.
// For K=768/N=768 GEMMs (o-proj, head): 768 blocks.
// ---------------------------------------------------------------------------
template<int EPI, int OUTF32>
__global__ __launch_bounds__(256, 4) void gemm64(
    const u16* __restrict__ A, const u16* __restrict__ Bt,
    const float* __restrict__ bias, void* __restrict__ Cout,
    int N_, int K_)
{
    __shared__ u16 lA[64 * 64];
    __shared__ u16 lB[64 * 64];
    const int tid  = threadIdx.x;
    const int lane = tid & 63;
    const int wave = tid >> 6;
    const int wr = wave >> 1, wc = wave & 1;
    const long row0 = (long)blockIdx.y * 64;
    const long col0 = (long)blockIdx.x * 64;

    f32x4 acc[2][2];
#pragma unroll
    for (int i = 0; i < 2; ++i)
#pragma unroll
        for (int j = 0; j < 2; ++j)
#pragma unroll
            for (int t = 0; t < 4; ++t) acc[i][j][t] = 0.f;

    int sRow[2], sKb[2];
#pragma unroll
    for (int t = 0; t < 2; ++t) {
        int byteoff = (wave * 2 + t) * 1024 + lane * 16;
        int r = byteoff >> 7;
        sRow[t] = r;
        sKb[t]  = (byteoff & 127) ^ ((r & 7) << 4);
    }
    const int laneRC = lane & 15;
    const int laneK2 = (lane >> 4) * 16;

    for (int k0 = 0; k0 < K_; k0 += 64) {
#pragma unroll
        for (int t = 0; t < 2; ++t) {
            const int cb = (wave * 2 + t) * 1024;
            gl_lds16(A  + (row0 + sRow[t]) * K_ + k0 + (sKb[t] >> 1), (char*)lA + cb);
            gl_lds16(Bt + (col0 + sRow[t]) * K_ + k0 + (sKb[t] >> 1), (char*)lB + cb);
        }
        __syncthreads();
#pragma unroll
        for (int kk = 0; kk < 2; ++kk) {
            bf16x8 af[2], bfr[2];
#pragma unroll
            for (int i = 0; i < 2; ++i) {
                int r = wr * 32 + i * 16 + laneRC;
                af[i] = *(const bf16x8*)((const char*)lA + r * 128 + ((kk * 64 + laneK2) ^ ((r & 7) << 4)));
            }
#pragma unroll
            for (int j = 0; j < 2; ++j) {
                int n = wc * 32 + j * 16 + laneRC;
                bfr[j] = *(const bf16x8*)((const char*)lB + n * 128 + ((kk * 64 + laneK2) ^ ((n & 7) << 4)));
            }
#pragma unroll
            for (int i = 0; i < 2; ++i)
#pragma unroll
                for (int j = 0; j < 2; ++j)
                    acc[i][j] = MFMA16(af[i], bfr[j], acc[i][j]);
        }
        __syncthreads();
    }

#pragma unroll
    for (int j = 0; j < 2; ++j) {
        const long cidx = col0 + wc * 32 + j * 16 + laneRC;
        const float bvv = bias[cidx];
#pragma unroll
        for (int i = 0; i < 2; ++i) {
            const long rbase = row0 + wr * 32 + i * 16 + ((lane >> 4) << 2);
#pragma unroll
            for (int t = 0; t < 4; ++t) {
                float v = acc[i][j][t] + bvv;
                if (EPI) v = gelu_f(v);
                const long off = (rbase + t) * N_ + cidx;
                if (OUTF32) ((float*)Cout)[off] = v;
                else        ((u16*)Cout)[off]  = f2bf(v);
            }
        }
    }
}

// ---------------------------------------------------------------------------
// Flash attention v5: SWAPPED QK^T (s = mfma(K,Q)) so each lane owns one
// q-row (q = lane&15): scalar mrun, corr aligned with O^T cols (no shuffles),
// key-consecutive P values packed as ds_write_b64 (16 scalar writes -> 4).
// Q pre-scaled by scale*log2e in the qkv GEMM -> P = exp2(s - m).
// P LDS content byte-identical to v4 (PV read code unchanged). lQ/lP shared
// buffer, 40KB LDS, 4 blocks/CU, ones-column MFMA row sums, defer-max.
// ---------------------------------------------------------------------------
__global__ __launch_bounds__(256, 4) void attn_fwd(
    const u16* __restrict__ qkv, u16* __restrict__ outb)
{
    __shared__ u16 lQP[64 * 64];         // Q at init, P afterwards
    __shared__ u16 lK[2][64 * 64];
    __shared__ u16 lVt[2][64 * 64];
    const int bh = blockIdx.x;           // b*12 + h
    const int b = bh / 12, h = bh % 12;
    const int q0 = blockIdx.y * 64;
    const int tid = threadIdx.x, lane = tid & 63, wave = tid >> 6;
    const long baseQ = (long)b * 2048 * 2304 + h * 64;
    const long baseK = baseQ + 768;
    const long baseV = baseQ + 1536;
    const int laneRC = lane & 15;
    const int laneK2 = (lane >> 4) * 16;

    int stR[2], stC[2];
#pragma unroll
    for (int t = 0; t < 2; ++t) {
        const int byteoff = (wave * 2 + t) * 1024 + lane * 16;
        const int r = byteoff >> 7;
        stR[t] = r;
        stC[t] = ((byteoff & 127) ^ ((r & 7) << 4)) >> 1;
    }

#define STAGEK(BUF, KB0) do {                                                    \
    _Pragma("unroll") for (int t = 0; t < 2; ++t)                                \
        gl_lds16(qkv + baseK + (long)((KB0) + stR[t]) * 2304 + stC[t],           \
                 (char*)lK[BUF] + (wave * 2 + t) * 1024);                        \
} while (0)

#pragma unroll
    for (int t = 0; t < 2; ++t)
        gl_lds16(qkv + baseQ + (long)(q0 + stR[t]) * 2304 + stC[t],
                 (char*)lQP + (wave * 2 + t) * 1024);
    STAGEK(0, 0);
    u16x8 vA0, vA1;
    {
        const u16x8* gv = (const u16x8*)(qkv + baseV + (long)lane * 2304 + wave * 16);
        vA0 = gv[0]; vA1 = gv[1];
    }
    __syncthreads();   // Q + K[0] landed, V-regs present

    bf16x8 qf[2];
#pragma unroll
    for (int kk = 0; kk < 2; ++kk) {
        int r = wave * 16 + laneRC;
        qf[kk] = *(const bf16x8*)((const char*)lQP + r * 128 + ((kk * 64 + laneK2) ^ ((r & 7) << 4)));
    }

    bf16x8 onesf;
#pragma unroll
    for (int j = 0; j < 8; ++j) onesf[j] = (__bf16)1.0f;

    float mrun = -1e30f;             // scalar: this lane's q-row running max
    f32x4 oacc[4], oaccS;            // oacc in O^T layout; oaccS = row sums
#pragma unroll
    for (int dc = 0; dc < 4; ++dc)
#pragma unroll
        for (int t = 0; t < 4; ++t) oacc[dc][t] = 0.f;
#pragma unroll
    for (int t = 0; t < 4; ++t) oaccS[t] = 0.f;

    u16x8 vB0 = vA0, vB1 = vA1;
    for (int kt = 0; kt < 32; ++kt) {
        const int cur = kt & 1;
        asm volatile("s_waitcnt vmcnt(0)" ::: "memory");
        SB0;
        {
            const int kv = lane, dg = wave;
            char* vt = (char*)lVt[cur];
#pragma unroll
            for (int j = 0; j < 8; ++j) {
                int d0 = dg * 16 + j;
                *(u16*)(vt + d0 * 128 + ((kv * 2) ^ ((d0 & 7) << 4))) = vA0[j];
                int d1 = dg * 16 + 8 + j;
                *(u16*)(vt + d1 * 128 + ((kv * 2) ^ ((d1 & 7) << 4))) = vA1[j];
            }
        }
        __builtin_amdgcn_s_barrier();
        SB0;
        if (kt + 1 < 32) {
            STAGEK(cur ^ 1, (kt + 1) * 64);
            const u16x8* gv = (const u16x8*)(qkv + baseV + (long)((kt + 1) * 64 + lane) * 2304 + wave * 16);
            vB0 = gv[0]; vB1 = gv[1];
        }
        const char* lKc = (const char*)lK[cur];
        const char* lVc = (const char*)lVt[cur];

        // S^T = K Q^T : lane holds q = laneRC, keys cb*16 + 4*(lane>>4) + r
        f32x4 s[4];
#pragma unroll
        for (int cb = 0; cb < 4; ++cb)
#pragma unroll
            for (int t = 0; t < 4; ++t) s[cb][t] = 0.f;
        __builtin_amdgcn_s_setprio(1);
#pragma unroll
        for (int kk = 0; kk < 2; ++kk) {
            bf16x8 kf[4];
#pragma unroll
            for (int cb = 0; cb < 4; ++cb) {
                int kr = cb * 16 + laneRC;
                kf[cb] = *(const bf16x8*)(lKc + kr * 128 + ((kk * 64 + laneK2) ^ ((kr & 7) << 4)));
            }
#pragma unroll
            for (int cb = 0; cb < 4; ++cb)
                s[cb] = MFMA16(kf[cb], qf[kk], s[cb]);   // swapped operands
        }
        __builtin_amdgcn_s_setprio(0);

        // defer-max check every 8th tile (scalar mrun; corr needs no shuffles)
        if ((kt & 7) == 0) {
            float pmax = s[0][0];
#pragma unroll
            for (int cb = 0; cb < 4; ++cb)
#pragma unroll
                for (int r = 0; r < 4; ++r) pmax = fmaxf(pmax, s[cb][r]);
            pmax = fmaxf(pmax, __shfl_xor(pmax, 16, 64));
            pmax = fmaxf(pmax, __shfl_xor(pmax, 32, 64));
            if (__ballot(pmax - mrun > 8.0f)) {
                const float mnew = fmaxf(mrun, pmax);
                const float corr = exp2f(mrun - mnew);
                mrun = mnew;
#pragma unroll
                for (int dc = 0; dc < 4; ++dc)
#pragma unroll
                    for (int t = 0; t < 4; ++t) oacc[dc][t] *= corr;
#pragma unroll
                for (int t = 0; t < 4; ++t) oaccS[t] *= corr;
            }
        }

        // P = exp2(s - m); pack 4 key-consecutive bf16 -> one ds_write_b64.
        // Content = P[q][key] at byte q*128 + (key*2 ^ ((q&7)<<4)) (as v4).
        {
            char* pbase = (char*)lQP + (wave * 16 + laneRC) * 128;
            const int pswz = (laneRC & 7) << 4;
            const int g8 = (lane >> 4) * 8;
#pragma unroll
            for (int c = 0; c < 4; ++c) {
                const uint32_t w0 = (uint32_t)f2bf(exp2f(s[c][0] - mrun))
                                  | ((uint32_t)f2bf(exp2f(s[c][1] - mrun)) << 16);
                const uint32_t w1 = (uint32_t)f2bf(exp2f(s[c][2] - mrun))
                                  | ((uint32_t)f2bf(exp2f(s[c][3] - mrun)) << 16);
                uint2 pk; pk.x = w0; pk.y = w1;
                *(uint2*)(pbase + ((c * 32 + g8) ^ pswz)) = pk;
            }
        }

        // O^T += V^T P^T ; sums += ones P^T   (unchanged)
        __builtin_amdgcn_s_setprio(1);
#pragma unroll
        for (int kk = 0; kk < 2; ++kk) {
            bf16x8 pf, vf[4];
            {
                int pr = wave * 16 + laneRC;
                pf = *(const bf16x8*)((const char*)lQP + pr * 128 + ((kk * 64 + laneK2) ^ ((pr & 7) << 4)));
            }
#pragma unroll
            for (int dc = 0; dc < 4; ++dc) {
                int d = dc * 16 + laneRC;
                vf[dc] = *(const bf16x8*)(lVc + d * 128 + ((kk * 64 + laneK2) ^ ((d & 7) << 4)));
            }
#pragma unroll
            for (int dc = 0; dc < 4; ++dc)
                oacc[dc] = MFMA16(vf[dc], pf, oacc[dc]);
            oaccS = MFMA16(onesf, pf, oaccS);
        }
        __builtin_amdgcn_s_setprio(0);
        vA0 = vB0; vA1 = vB1;
    }
#undef STAGEK

    // epilogue: lane holds q = lane&15, d-rows dc*16 + (lane>>4)*4 + t
    const float inv = 1.0f / oaccS[0];
    const long rowq = (long)b * 2048 + q0 + wave * 16 + (lane & 15);
#pragma unroll
    for (int dc = 0; dc < 4; ++dc) {
        const int colb = h * 64 + dc * 16 + ((lane >> 4) << 2);
        ushort4 st;
        st.x = f2bf(oacc[dc][0] * inv);
        st.y = f2bf(oacc[dc][1] * inv);
        st.z = f2bf(oacc[dc][2] * inv);
        st.w = f2bf(oacc[dc][3] * inv);
        *(ushort4*)(outb + rowq * 768 + colb) = st;
    }
}

// ---------------------------------------------------------------------------
// fused residual-add + NP partial-sums + LayerNorm; wave-per-row, float4 loads
// ---------------------------------------------------------------------------
template<int NP>
__global__ __launch_bounds__(256) void ln_fused(
    const float* __restrict__ a, const float* __restrict__ parts, long pstride,
    const float* __restrict__ g, const float* __restrict__ be,
    float* __restrict__ outf, u16* __restrict__ outb)
{
    const int wave = threadIdx.x >> 6, lane = threadIdx.x & 63;
    const int row = blockIdx.x * 4 + wave;
    const size_t rbase = (size_t)row * 768;
    float4 v[3];
    float s1 = 0.f, s2 = 0.f;
#pragma unroll
    for (int i = 0; i < 3; ++i) {
        const int c = lane * 4 + i * 256;
        float4 x = *(const float4*)(a + rbase + c);
#pragma unroll
        for (int p = 0; p < NP; ++p) {
            const float4 y = *(const float4*)(parts + (size_t)p * pstride + rbase + c);
            x.x += y.x; x.y += y.y; x.z += y.z; x.w += y.w;
        }
        v[i] = x;
        s1 += x.x + x.y + x.z + x.w;
        s2 += x.x * x.x + x.y * x.y + x.z * x.z + x.w * x.w;
    }
#pragma unroll
    for (int m = 1; m < 64; m <<= 1) { s1 += __shfl_xor(s1, m, 64); s2 += __shfl_xor(s2, m, 64); }
    const float mean = s1 * (1.f / 768.f);
    const float var  = s2 * (1.f / 768.f) - mean * mean;
    const float rstd = rsqrtf(var + 1e-5f);
#pragma unroll
    for (int i = 0; i < 3; ++i) {
        const int c = lane * 4 + i * 256;
        const float4 gg = *(const float4*)(g + c);
        const float4 bb = *(const float4*)(be + c);
        float4 y;
        y.x = (v[i].x - mean) * rstd * gg.x + bb.x;
        y.y = (v[i].y - mean) * rstd * gg.y + bb.y;
        y.z = (v[i].z - mean) * rstd * gg.z + bb.z;
        y.w = (v[i].w - mean) * rstd * gg.w + bb.w;
        if (outf) *(float4*)(outf + rbase + c) = y;
        ushort4 u; u.x = f2bf(y.x); u.y = f2bf(y.y); u.z = f2bf(y.z); u.w = f2bf(y.w);
        *(ushort4*)(outb + rbase + c) = u;
    }
}

// ---------------------------------------------------------------------------
// ONE prep launch: 13 weight transposes (blocks [0,14400)) + embB cvt +
// embed+PE + bias concat (blocks [14400, 14400+36306)).
// ---------------------------------------------------------------------------
struct PrepArgs {
    const float* tsrc[13]; u16* tdst[13];
    const float* emb; u16* embB;
    const int* ids; float* xf; u16* xb;
    const float* bq; const float* bk; const float* bv; float* bqkv;
};
__global__ __launch_bounds__(256) void prep_all(PrepArgs pa)
{
    const int bid = blockIdx.x;
    if (bid < 14400) {
        int z, bx, by, R, C;
        if (bid < 5184)       { z = bid / 576;              int r = bid - z * 576;    bx = r % 24; by = r / 24; R = 768;  C = 768;  }
        else if (bid < 9792)  { z = 9 + (bid - 5184) / 2304;  int r = (bid - 5184) % 2304; bx = r % 96; by = r / 96; R = 768;  C = 3072; }
        else                  { z = 11 + (bid - 9792) / 2304; int r = (bid - 9792) % 2304; bx = r % 24; by = r / 24; R = 3072; C = 768;  }
        __shared__ float t[32][33];
        const float* in = pa.tsrc[z];
        u16* out = pa.tdst[z];
        const int c0 = bx * 32, r0 = by * 32;
        const int tx = threadIdx.x & 31, ty = threadIdx.x >> 5;
#pragma unroll
        for (int i = 0; i < 4; ++i)
            t[ty + 8 * i][tx] = in[(size_t)(r0 + ty + 8 * i) * C + c0 + tx];
        __syncthreads();
#pragma unroll
        for (int i = 0; i < 4; ++i)
            out[(size_t)(c0 + ty + 8 * i) * R + r0 + tx] = f2bf(t[tx][ty + 8 * i]);
        return;
    }
    const long A = 6144000;      // V*D/4 vec4 conversions
    const long B = 3145728;      // 4096*768 embed elements
    long t = (long)(bid - 14400) * 256 + threadIdx.x;
    if (t < A) {
        const long i = t * 4;
        const float4 f = *(const float4*)(pa.emb + i);
        ushort4 u; u.x = f2bf(f.x); u.y = f2bf(f.y); u.z = f2bf(f.z); u.w = f2bf(f.w);
        *(ushort4*)(pa.embB + i) = u;
    } else if (t < A + B) {
        const int idx = (int)(t - A);
        const int row = idx / 768, d = idx - row * 768;
        const int s = row & 2047;
        const float e = pa.emb[(long)pa.ids[row] * 768 + d];
        const int j = d >> 1;
        const float ang = (float)s * __expf(-0.011992630692677324f * (float)(4 * j));
        const float pe = (d & 1) ? __cosf(ang) : __sinf(ang);
        const float v = e + pe;
        pa.xf[idx] = v;
        pa.xb[idx] = f2bf(v);
    } else {
        const int i = (int)(t - A - B);
        if (i < 4608) {
            int l = i / 2304, j = i - l * 2304;
            float v = (j < 768) ? pa.bq[l * 768 + j]
                    : (j < 1536) ? pa.bk[l * 768 + j - 768]
                    : pa.bv[l * 768 + j - 1536];
            pa.bqkv[i] = v;
        }
    }
}

// ---------------------------------------------------------------------------
extern "C" void kernel_launch(void* const* d_in, const int* in_sizes, int n_in,
                              void* d_out, int out_size, void* d_ws, size_t ws_size,
                              hipStream_t stream)
{
    const int S = 2048, D = 768, H = 12, L = 2, V = 32000, DF = 3072, M = 4096, NQKV = 2304;
    (void)in_sizes; (void)n_in; (void)out_size; (void)ws_size; (void)H; (void)S;

    const int*   ids  = (const int*)  d_in[0];
    const float* emb  = (const float*)d_in[1];
    const float* Wq   = (const float*)d_in[2];
    const float* bq   = (const float*)d_in[3];
    const float* Wk   = (const float*)d_in[4];
    const float* bk   = (const float*)d_in[5];
    const float* Wv   = (const float*)d_in[6];
    const float* bv   = (const float*)d_in[7];
    const float* Wo   = (const float*)d_in[8];
    const float* bo   = (const float*)d_in[9];
    const float* ln1g = (const float*)d_in[10];
    const float* ln1b = (const float*)d_in[11];
    const float* W1   = (const float*)d_in[12];
    const float* b1   = (const float*)d_in[13];
    const float* W2   = (const float*)d_in[14];
    const float* b2   = (const float*)d_in[15];
    const float* ln2g = (const float*)d_in[16];
    const float* ln2b = (const float*)d_in[17];
    const float* Wd   = (const float*)d_in[18];
    const float* bd   = (const float*)d_in[19];
    const float* lnmg = (const float*)d_in[20];
    const float* lnmb = (const float*)d_in[21];
    const float* decb = (const float*)d_in[22];

    char* p = (char*)d_ws;
    auto carve = [&](size_t bytes) { char* r = p; p += (bytes + 255) & ~(size_t)255; return r; };
    u16*   embB  = (u16*)  carve((size_t)V * D * 2);
    u16*   wqkvT = (u16*)  carve((size_t)L * NQKV * D * 2);
    float* bqkv  = (float*)carve((size_t)L * NQKV * 4);
    u16*   woT   = (u16*)  carve((size_t)L * D * D * 2);
    u16*   w1T   = (u16*)  carve((size_t)L * DF * D * 2);
    u16*   w2T   = (u16*)  carve((size_t)L * D * DF * 2);
    u16*   wdT   = (u16*)  carve((size_t)D * D * 2);
    float* xf    = (float*)carve((size_t)M * D * 4);
    u16*   xb    = (u16*)  carve((size_t)M * D * 2);
    u16*   qkvB  = (u16*)  carve((size_t)M * NQKV * 2);
    u16*   aoB   = (u16*)  carve((size_t)M * D * 2);
    float* tmpf  = (float*)carve((size_t)M * D * 4 * 4);   // split-K partials
    u16*   hB    = (u16*)  carve((size_t)M * DF * 2);

    {   // single prep launch: 13 transposes + cvt + embed/PE + bias concat
        PrepArgs pa;
        for (int l = 0; l < L; ++l) {
            pa.tsrc[l * 4 + 0] = Wq + (size_t)l * D * D; pa.tdst[l * 4 + 0] = wqkvT + (size_t)l * NQKV * D;
            pa.tsrc[l * 4 + 1] = Wk + (size_t)l * D * D; pa.tdst[l * 4 + 1] = wqkvT + (size_t)l * NQKV * D + (size_t)D * D;
            pa.tsrc[l * 4 + 2] = Wv + (size_t)l * D * D; pa.tdst[l * 4 + 2] = wqkvT + (size_t)l * NQKV * D + (size_t)2 * D * D;
            pa.tsrc[l * 4 + 3] = Wo + (size_t)l * D * D; pa.tdst[l * 4 + 3] = woT + (size_t)l * D * D;
        }
        pa.tsrc[8]  = Wd;                    pa.tdst[8]  = wdT;
        pa.tsrc[9]  = W1;                    pa.tdst[9]  = w1T;
        pa.tsrc[10] = W1 + (size_t)D * DF;   pa.tdst[10] = w1T + (size_t)DF * D;
        pa.tsrc[11] = W2;                    pa.tdst[11] = w2T;
        pa.tsrc[12] = W2 + (size_t)DF * D;   pa.tdst[12] = w2T + (size_t)D * DF;
        pa.emb = emb; pa.embB = embB;
        pa.ids = ids; pa.xf = xf; pa.xb = xb;
        pa.bq = bq; pa.bk = bk; pa.bv = bv; pa.bqkv = bqkv;
        prep_all<<<14400 + 36306, 256, 0, stream>>>(pa);
    }

    // q pre-scale: 1/sqrt(768) * log2(e)  (attention uses exp2)
    const float qscale = 0.036084391824351615f * 1.4426950408889634f;
    const long PSTR = (long)M * D;
    for (int l = 0; l < L; ++l) {
        gemm_bf16<0, 0, 0, 1, 1><<<dim3(NQKV / 128, M / 128), 256, 0, stream>>>(xb, wqkvT + (size_t)l * NQKV * D, bqkv + l * NQKV, qkvB, NQKV, D, qscale);
        attn_fwd<<<dim3(24, 32), 256, 0, stream>>>(qkvB, aoB);
        gemm64<0, 1><<<dim3(D / 64, M / 64), 256, 0, stream>>>(aoB, woT + (size_t)l * D * D, bo + l * D, tmpf, D, D);
        ln_fused<1><<<M / 4, 256, 0, stream>>>(xf, tmpf, PSTR, ln1g + l * D, ln1b + l * D, xf, xb);
        gemm_bf16<1, 0, 0, 1, 0><<<dim3(DF / 128, M / 128), 256, 0, stream>>>(xb, w1T + (size_t)l * DF * D, b1 + l * DF, hB, DF, D, 1.0f);
        gemm_bf16<0, 1, 0, 2, 0><<<dim3(D / 128, M / 128, 2), 256, 0, stream>>>(hB, w2T + (size_t)l * D * DF, b2 + l * D, tmpf, D, DF, 1.0f);
        ln_fused<2><<<M / 4, 256, 0, stream>>>(xf, tmpf, PSTR, ln2g + l * D, ln2b + l * D, xf, xb);
    }
    gemm64<1, 1><<<dim3(D / 64, M / 64), 256, 0, stream>>>(xb, wdT, bd, tmpf, D, D);
    ln_fused<0><<<M / 4, 256, 0, stream>>>(tmpf, nullptr, 0, lnmg, lnmb, nullptr, aoB);
    gemm_bf16<0, 1, 1, 1, 0><<<V / 128 * 32, 256, 0, stream>>>(aoB, embB, decb, (float*)d_out, V, D, 1.0f);
}

// Round 11
// 708.183 us; speedup vs baseline: 1.0444x; 1.0444x over previous
//
#include <hip/hip_runtime.h>
#include <hip/hip_bf16.h>
#include <cstdint>

typedef __bf16 bf16x8 __attribute__((ext_vector_type(8)));
typedef float  f32x4  __attribute__((ext_vector_type(4)));
typedef unsigned short u16;
typedef u16 u16x8 __attribute__((ext_vector_type(8)));

__device__ __forceinline__ u16 f2bf(float f) {
    union { float f; uint32_t u; } x{f};
    uint32_t u = x.u;
    return (u16)((u + 0x7fffu + ((u >> 16) & 1u)) >> 16);
}

__device__ __forceinline__ float fexp2(float x) {   // raw v_exp_f32 (HW exp2)
    return __builtin_amdgcn_exp2f(x);
}

__device__ __forceinline__ float gelu_f(float x) {
    return 0.5f * x * (1.0f + erff(x * 0.70710678118654752f));
}

// async global->LDS, 16B per lane; LDS dest is wave-uniform base + lane*16
__device__ __forceinline__ void gl_lds16(const void* g, void* l) {
    __builtin_amdgcn_global_load_lds(
        (__attribute__((address_space(1))) void*)(void*)g,
        (__attribute__((address_space(3))) void*)l, 16, 0, 0);
}

#define MFMA16(a, b, c) __builtin_amdgcn_mfma_f32_16x16x32_bf16((a), (b), (c), 0, 0, 0)
#define SB0 __builtin_amdgcn_sched_barrier(0)

// ---------------------------------------------------------------------------
// 128x128 GEMM, BK=64, 4 waves (2x2), single-buffered (measured best).
// LOC=1: linear grid remapped into 512-block chunks for L3 B-residency
// (decoder). SPLITK>1: grid.z splits K, partials to Cout + z*4096*N_.
// QS=1: multiply cols<768 by qs (pre-scales attention q by scale*log2e).
// ---------------------------------------------------------------------------
template<int EPI, int OUTF32, int LOC, int SPLITK, int QS>
__global__ __launch_bounds__(256, 2) void gemm_bf16(
    const u16* __restrict__ A, const u16* __restrict__ Bt,
    const float* __restrict__ bias, void* __restrict__ Cout,
    int N_, int K_, float qs)
{
    __shared__ u16 lA[128 * 64];
    __shared__ u16 lB[128 * 64];
    const int tid  = threadIdx.x;
    const int lane = tid & 63;
    const int wave = tid >> 6;
    const int wr = wave >> 1, wc = wave & 1;
    long row0, col0;
    if (LOC) {   // linear grid: chunk = 512 blocks = 32 rows x 16 cols, row fastest
        const int bid = blockIdx.x;
        const int chunk = bid >> 9, rem = bid & 511;
        row0 = (long)(rem & 31) * 128;
        col0 = (long)(chunk * 16 + (rem >> 5)) * 128;
    } else {
        row0 = (long)blockIdx.y * 128;
        col0 = (long)blockIdx.x * 128;
    }
    const int KS = K_ / SPLITK;
    const int kz = (SPLITK > 1) ? blockIdx.z * KS : 0;

    f32x4 acc[4][4];
#pragma unroll
    for (int i = 0; i < 4; ++i)
#pragma unroll
        for (int j = 0; j < 4; ++j)
#pragma unroll
            for (int t = 0; t < 4; ++t) acc[i][j][t] = 0.f;

    int sRow[4], sKb[4];
#pragma unroll
    for (int t = 0; t < 4; ++t) {
        int byteoff = (wave * 4 + t) * 1024 + lane * 16;
        int r = byteoff >> 7;
        sRow[t] = r;
        sKb[t]  = (byteoff & 127) ^ ((r & 7) << 4);
    }
    const int laneRC = lane & 15;
    const int laneK2 = (lane >> 4) * 16;

    for (int k0 = kz; k0 < kz + KS; k0 += 64) {
#pragma unroll
        for (int t = 0; t < 4; ++t) {
            const int cb = (wave * 4 + t) * 1024;
            gl_lds16(A  + (row0 + sRow[t]) * K_ + k0 + (sKb[t] >> 1), (char*)lA + cb);
            gl_lds16(Bt + (col0 + sRow[t]) * K_ + k0 + (sKb[t] >> 1), (char*)lB + cb);
        }
        __syncthreads();
#pragma unroll
        for (int kk = 0; kk < 2; ++kk) {
            bf16x8 af[4], bfr[4];
#pragma unroll
            for (int i = 0; i < 4; ++i) {
                int r = wr * 64 + i * 16 + laneRC;
                af[i] = *(const bf16x8*)((const char*)lA + r * 128 + ((kk * 64 + laneK2) ^ ((r & 7) << 4)));
            }
#pragma unroll
            for (int j = 0; j < 4; ++j) {
                int n = wc * 64 + j * 16 + laneRC;
                bfr[j] = *(const bf16x8*)((const char*)lB + n * 128 + ((kk * 64 + laneK2) ^ ((n & 7) << 4)));
            }
#pragma unroll
            for (int i = 0; i < 4; ++i)
#pragma unroll
                for (int j = 0; j < 4; ++j)
                    acc[i][j] = MFMA16(af[i], bfr[j], acc[i][j]);
        }
        __syncthreads();
    }

    float* outF = (float*)Cout + (SPLITK > 1 ? (long)blockIdx.z * 4096 * N_ : 0);
    const float qmul = (QS && col0 < 768) ? qs : 1.0f;
#pragma unroll
    for (int j = 0; j < 4; ++j) {
        const long cidx = col0 + wc * 64 + j * 16 + laneRC;
        const float bvv = (SPLITK == 1 || blockIdx.z == 0) ? bias[cidx] : 0.f;
#pragma unroll
        for (int i = 0; i < 4; ++i) {
            const long rbase = row0 + wr * 64 + i * 16 + ((lane >> 4) << 2);
#pragma unroll
            for (int t = 0; t < 4; ++t) {
                float v = acc[i][j][t] + bvv;
                if (QS) v *= qmul;
                if (EPI) v = gelu_f(v);
                const long off = (rbase + t) * N_ + cidx;
                if (OUTF32) outF[off] = v;
                else        ((u16*)Cout)[off] = f2bf(v);
            }
        }
    }
}

// ---------------------------------------------------------------------------
// 64x64 GEMM, BK=64, 4 waves (2x2, wave-tile 32x32), 16 KiB LDS.
// For K=768/N=768 GEMMs (o-proj, head): 768 blocks.
// ---------------------------------------------------------------------------
template<int EPI, int OUTF32>
__global__ __launch_bounds__(256, 4) void gemm64(
    const u16* __restrict__ A, const u16* __restrict__ Bt,
    const float* __restrict__ bias, void* __restrict__ Cout,
    int N_, int K_)
{
    __shared__ u16 lA[64 * 64];
    __shared__ u16 lB[64 * 64];
    const int tid  = threadIdx.x;
    const int lane = tid & 63;
    const int wave = tid >> 6;
    const int wr = wave >> 1, wc = wave & 1;
    const long row0 = (long)blockIdx.y * 64;
    const long col0 = (long)blockIdx.x * 64;

    f32x4 acc[2][2];
#pragma unroll
    for (int i = 0; i < 2; ++i)
#pragma unroll
        for (int j = 0; j < 2; ++j)
#pragma unroll
            for (int t = 0; t < 4; ++t) acc[i][j][t] = 0.f;

    int sRow[2], sKb[2];
#pragma unroll
    for (int t = 0; t < 2; ++t) {
        int byteoff = (wave * 2 + t) * 1024 + lane * 16;
        int r = byteoff >> 7;
        sRow[t] = r;
        sKb[t]  = (byteoff & 127) ^ ((r & 7) << 4);
    }
    const int laneRC = lane & 15;
    const int laneK2 = (lane >> 4) * 16;

    for (int k0 = 0; k0 < K_; k0 += 64) {
#pragma unroll
        for (int t = 0; t < 2; ++t) {
            const int cb = (wave * 2 + t) * 1024;
            gl_lds16(A  + (row0 + sRow[t]) * K_ + k0 + (sKb[t] >> 1), (char*)lA + cb);
            gl_lds16(Bt + (col0 + sRow[t]) * K_ + k0 + (sKb[t] >> 1), (char*)lB + cb);
        }
        __syncthreads();
#pragma unroll
        for (int kk = 0; kk < 2; ++kk) {
            bf16x8 af[2], bfr[2];
#pragma unroll
            for (int i = 0; i < 2; ++i) {
                int r = wr * 32 + i * 16 + laneRC;
                af[i] = *(const bf16x8*)((const char*)lA + r * 128 + ((kk * 64 + laneK2) ^ ((r & 7) << 4)));
            }
#pragma unroll
            for (int j = 0; j < 2; ++j) {
                int n = wc * 32 + j * 16 + laneRC;
                bfr[j] = *(const bf16x8*)((const char*)lB + n * 128 + ((kk * 64 + laneK2) ^ ((n & 7) << 4)));
            }
#pragma unroll
            for (int i = 0; i < 2; ++i)
#pragma unroll
                for (int j = 0; j < 2; ++j)
                    acc[i][j] = MFMA16(af[i], bfr[j], acc[i][j]);
        }
        __syncthreads();
    }

#pragma unroll
    for (int j = 0; j < 2; ++j) {
        const long cidx = col0 + wc * 32 + j * 16 + laneRC;
        const float bvv = bias[cidx];
#pragma unroll
        for (int i = 0; i < 2; ++i) {
            const long rbase = row0 + wr * 32 + i * 16 + ((lane >> 4) << 2);
#pragma unroll
            for (int t = 0; t < 4; ++t) {
                float v = acc[i][j][t] + bvv;
                if (EPI) v = gelu_f(v);
                const long off = (rbase + t) * N_ + cidx;
                if (OUTF32) ((float*)Cout)[off] = v;
                else        ((u16*)Cout)[off]  = f2bf(v);
            }
        }
    }
}

// ---------------------------------------------------------------------------
// Flash attention v5b: v5 structure (swapped QK^T, scalar mrun, packed
// ds_write_b64 P, exp2-domain) with RAW v_exp_f32 via __builtin_amdgcn_exp2f
// (r10's libm exp2f carried ~4 extra fixup ops per call = the regression).
// ---------------------------------------------------------------------------
__global__ __launch_bounds__(256, 4) void attn_fwd(
    const u16* __restrict__ qkv, u16* __restrict__ outb)
{
    __shared__ u16 lQP[64 * 64];         // Q at init, P afterwards
    __shared__ u16 lK[2][64 * 64];
    __shared__ u16 lVt[2][64 * 64];
    const int bh = blockIdx.x;           // b*12 + h
    const int b = bh / 12, h = bh % 12;
    const int q0 = blockIdx.y * 64;
    const int tid = threadIdx.x, lane = tid & 63, wave = tid >> 6;
    const long baseQ = (long)b * 2048 * 2304 + h * 64;
    const long baseK = baseQ + 768;
    const long baseV = baseQ + 1536;
    const int laneRC = lane & 15;
    const int laneK2 = (lane >> 4) * 16;

    int stR[2], stC[2];
#pragma unroll
    for (int t = 0; t < 2; ++t) {
        const int byteoff = (wave * 2 + t) * 1024 + lane * 16;
        const int r = byteoff >> 7;
        stR[t] = r;
        stC[t] = ((byteoff & 127) ^ ((r & 7) << 4)) >> 1;
    }

#define STAGEK(BUF, KB0) do {                                                    \
    _Pragma("unroll") for (int t = 0; t < 2; ++t)                                \
        gl_lds16(qkv + baseK + (long)((KB0) + stR[t]) * 2304 + stC[t],           \
                 (char*)lK[BUF] + (wave * 2 + t) * 1024);                        \
} while (0)

#pragma unroll
    for (int t = 0; t < 2; ++t)
        gl_lds16(qkv + baseQ + (long)(q0 + stR[t]) * 2304 + stC[t],
                 (char*)lQP + (wave * 2 + t) * 1024);
    STAGEK(0, 0);
    u16x8 vA0, vA1;
    {
        const u16x8* gv = (const u16x8*)(qkv + baseV + (long)lane * 2304 + wave * 16);
        vA0 = gv[0]; vA1 = gv[1];
    }
    __syncthreads();   // Q + K[0] landed, V-regs present

    bf16x8 qf[2];
#pragma unroll
    for (int kk = 0; kk < 2; ++kk) {
        int r = wave * 16 + laneRC;
        qf[kk] = *(const bf16x8*)((const char*)lQP + r * 128 + ((kk * 64 + laneK2) ^ ((r & 7) << 4)));
    }

    bf16x8 onesf;
#pragma unroll
    for (int j = 0; j < 8; ++j) onesf[j] = (__bf16)1.0f;

    float mrun = -1e30f;             // scalar: this lane's q-row running max
    f32x4 oacc[4], oaccS;            // oacc in O^T layout; oaccS = row sums
#pragma unroll
    for (int dc = 0; dc < 4; ++dc)
#pragma unroll
        for (int t = 0; t < 4; ++t) oacc[dc][t] = 0.f;
#pragma unroll
    for (int t = 0; t < 4; ++t) oaccS[t] = 0.f;

    u16x8 vB0 = vA0, vB1 = vA1;
    for (int kt = 0; kt < 32; ++kt) {
        const int cur = kt & 1;
        asm volatile("s_waitcnt vmcnt(0)" ::: "memory");
        SB0;
        {
            const int kv = lane, dg = wave;
            char* vt = (char*)lVt[cur];
#pragma unroll
            for (int j = 0; j < 8; ++j) {
                int d0 = dg * 16 + j;
                *(u16*)(vt + d0 * 128 + ((kv * 2) ^ ((d0 & 7) << 4))) = vA0[j];
                int d1 = dg * 16 + 8 + j;
                *(u16*)(vt + d1 * 128 + ((kv * 2) ^ ((d1 & 7) << 4))) = vA1[j];
            }
        }
        __builtin_amdgcn_s_barrier();
        SB0;
        if (kt + 1 < 32) {
            STAGEK(cur ^ 1, (kt + 1) * 64);
            const u16x8* gv = (const u16x8*)(qkv + baseV + (long)((kt + 1) * 64 + lane) * 2304 + wave * 16);
            vB0 = gv[0]; vB1 = gv[1];
        }
        const char* lKc = (const char*)lK[cur];
        const char* lVc = (const char*)lVt[cur];

        // S^T = K Q^T : lane holds q = laneRC, keys cb*16 + 4*(lane>>4) + r
        f32x4 s[4];
#pragma unroll
        for (int cb = 0; cb < 4; ++cb)
#pragma unroll
            for (int t = 0; t < 4; ++t) s[cb][t] = 0.f;
        __builtin_amdgcn_s_setprio(1);
#pragma unroll
        for (int kk = 0; kk < 2; ++kk) {
            bf16x8 kf[4];
#pragma unroll
            for (int cb = 0; cb < 4; ++cb) {
                int kr = cb * 16 + laneRC;
                kf[cb] = *(const bf16x8*)(lKc + kr * 128 + ((kk * 64 + laneK2) ^ ((kr & 7) << 4)));
            }
#pragma unroll
            for (int cb = 0; cb < 4; ++cb)
                s[cb] = MFMA16(kf[cb], qf[kk], s[cb]);   // swapped operands
        }
        __builtin_amdgcn_s_setprio(0);

        // defer-max check every 8th tile (scalar mrun; corr needs no shuffles)
        if ((kt & 7) == 0) {
            float pmax = s[0][0];
#pragma unroll
            for (int cb = 0; cb < 4; ++cb)
#pragma unroll
                for (int r = 0; r < 4; ++r) pmax = fmaxf(pmax, s[cb][r]);
            pmax = fmaxf(pmax, __shfl_xor(pmax, 16, 64));
            pmax = fmaxf(pmax, __shfl_xor(pmax, 32, 64));
            if (__ballot(pmax - mrun > 8.0f)) {
                const float mnew = fmaxf(mrun, pmax);
                const float corr = fexp2(mrun - mnew);
                mrun = mnew;
#pragma unroll
                for (int dc = 0; dc < 4; ++dc)
#pragma unroll
                    for (int t = 0; t < 4; ++t) oacc[dc][t] *= corr;
#pragma unroll
                for (int t = 0; t < 4; ++t) oaccS[t] *= corr;
            }
        }

        // P = exp2(s - m) via raw v_exp_f32; 4 key-consecutive bf16 per
        // ds_write_b64. Content = P[q][key] at q*128 + (key*2 ^ ((q&7)<<4)).
        {
            char* pbase = (char*)lQP + (wave * 16 + laneRC) * 128;
            const int pswz = (laneRC & 7) << 4;
            const int g8 = (lane >> 4) * 8;
#pragma unroll
            for (int c = 0; c < 4; ++c) {
                const uint32_t w0 = (uint32_t)f2bf(fexp2(s[c][0] - mrun))
                                  | ((uint32_t)f2bf(fexp2(s[c][1] - mrun)) << 16);
                const uint32_t w1 = (uint32_t)f2bf(fexp2(s[c][2] - mrun))
                                  | ((uint32_t)f2bf(fexp2(s[c][3] - mrun)) << 16);
                uint2 pk; pk.x = w0; pk.y = w1;
                *(uint2*)(pbase + ((c * 32 + g8) ^ pswz)) = pk;
            }
        }

        // O^T += V^T P^T ; sums += ones P^T
        __builtin_amdgcn_s_setprio(1);
#pragma unroll
        for (int kk = 0; kk < 2; ++kk) {
            bf16x8 pf, vf[4];
            {
                int pr = wave * 16 + laneRC;
                pf = *(const bf16x8*)((const char*)lQP + pr * 128 + ((kk * 64 + laneK2) ^ ((pr & 7) << 4)));
            }
#pragma unroll
            for (int dc = 0; dc < 4; ++dc) {
                int d = dc * 16 + laneRC;
                vf[dc] = *(const bf16x8*)(lVc + d * 128 + ((kk * 64 + laneK2) ^ ((d & 7) << 4)));
            }
#pragma unroll
            for (int dc = 0; dc < 4; ++dc)
                oacc[dc] = MFMA16(vf[dc], pf, oacc[dc]);
            oaccS = MFMA16(onesf, pf, oaccS);
        }
        __builtin_amdgcn_s_setprio(0);
        vA0 = vB0; vA1 = vB1;
    }
#undef STAGEK

    // epilogue: lane holds q = lane&15, d-rows dc*16 + (lane>>4)*4 + t
    const float inv = 1.0f / oaccS[0];
    const long rowq = (long)b * 2048 + q0 + wave * 16 + (lane & 15);
#pragma unroll
    for (int dc = 0; dc < 4; ++dc) {
        const int colb = h * 64 + dc * 16 + ((lane >> 4) << 2);
        ushort4 st;
        st.x = f2bf(oacc[dc][0] * inv);
        st.y = f2bf(oacc[dc][1] * inv);
        st.z = f2bf(oacc[dc][2] * inv);
        st.w = f2bf(oacc[dc][3] * inv);
        *(ushort4*)(outb + rowq * 768 + colb) = st;
    }
}

// ---------------------------------------------------------------------------
// fused residual-add + NP partial-sums + LayerNorm; wave-per-row, float4 loads
// ---------------------------------------------------------------------------
template<int NP>
__global__ __launch_bounds__(256) void ln_fused(
    const float* __restrict__ a, const float* __restrict__ parts, long pstride,
    const float* __restrict__ g, const float* __restrict__ be,
    float* __restrict__ outf, u16* __restrict__ outb)
{
    const int wave = threadIdx.x >> 6, lane = threadIdx.x & 63;
    const int row = blockIdx.x * 4 + wave;
    const size_t rbase = (size_t)row * 768;
    float4 v[3];
    float s1 = 0.f, s2 = 0.f;
#pragma unroll
    for (int i = 0; i < 3; ++i) {
        const int c = lane * 4 + i * 256;
        float4 x = *(const float4*)(a + rbase + c);
#pragma unroll
        for (int p = 0; p < NP; ++p) {
            const float4 y = *(const float4*)(parts + (size_t)p * pstride + rbase + c);
            x.x += y.x; x.y += y.y; x.z += y.z; x.w += y.w;
        }
        v[i] = x;
        s1 += x.x + x.y + x.z + x.w;
        s2 += x.x * x.x + x.y * x.y + x.z * x.z + x.w * x.w;
    }
#pragma unroll
    for (int m = 1; m < 64; m <<= 1) { s1 += __shfl_xor(s1, m, 64); s2 += __shfl_xor(s2, m, 64); }
    const float mean = s1 * (1.f / 768.f);
    const float var  = s2 * (1.f / 768.f) - mean * mean;
    const float rstd = rsqrtf(var + 1e-5f);
#pragma unroll
    for (int i = 0; i < 3; ++i) {
        const int c = lane * 4 + i * 256;
        const float4 gg = *(const float4*)(g + c);
        const float4 bb = *(const float4*)(be + c);
        float4 y;
        y.x = (v[i].x - mean) * rstd * gg.x + bb.x;
        y.y = (v[i].y - mean) * rstd * gg.y + bb.y;
        y.z = (v[i].z - mean) * rstd * gg.z + bb.z;
        y.w = (v[i].w - mean) * rstd * gg.w + bb.w;
        if (outf) *(float4*)(outf + rbase + c) = y;
        ushort4 u; u.x = f2bf(y.x); u.y = f2bf(y.y); u.z = f2bf(y.z); u.w = f2bf(y.w);
        *(ushort4*)(outb + rbase + c) = u;
    }
}

// ---------------------------------------------------------------------------
// ONE prep launch: 13 weight transposes (blocks [0,14400)) + embB cvt +
// embed+PE + bias concat (blocks [14400, 14400+36306)).
// ---------------------------------------------------------------------------
struct PrepArgs {
    const float* tsrc[13]; u16* tdst[13];
    const float* emb; u16* embB;
    const int* ids; float* xf; u16* xb;
    const float* bq; const float* bk; const float* bv; float* bqkv;
};
__global__ __launch_bounds__(256) void prep_all(PrepArgs pa)
{
    const int bid = blockIdx.x;
    if (bid < 14400) {
        int z, bx, by, R, C;
        if (bid < 5184)       { z = bid / 576;              int r = bid - z * 576;    bx = r % 24; by = r / 24; R = 768;  C = 768;  }
        else if (bid < 9792)  { z = 9 + (bid - 5184) / 2304;  int r = (bid - 5184) % 2304; bx = r % 96; by = r / 96; R = 768;  C = 3072; }
        else                  { z = 11 + (bid - 9792) / 2304; int r = (bid - 9792) % 2304; bx = r % 24; by = r / 24; R = 3072; C = 768;  }
        __shared__ float t[32][33];
        const float* in = pa.tsrc[z];
        u16* out = pa.tdst[z];
        const int c0 = bx * 32, r0 = by * 32;
        const int tx = threadIdx.x & 31, ty = threadIdx.x >> 5;
#pragma unroll
        for (int i = 0; i < 4; ++i)
            t[ty + 8 * i][tx] = in[(size_t)(r0 + ty + 8 * i) * C + c0 + tx];
        __syncthreads();
#pragma unroll
        for (int i = 0; i < 4; ++i)
            out[(size_t)(c0 + ty + 8 * i) * R + r0 + tx] = f2bf(t[tx][ty + 8 * i]);
        return;
    }
    const long A = 6144000;      // V*D/4 vec4 conversions
    const long B = 3145728;      // 4096*768 embed elements
    long t = (long)(bid - 14400) * 256 + threadIdx.x;
    if (t < A) {
        const long i = t * 4;
        const float4 f = *(const float4*)(pa.emb + i);
        ushort4 u; u.x = f2bf(f.x); u.y = f2bf(f.y); u.z = f2bf(f.z); u.w = f2bf(f.w);
        *(ushort4*)(pa.embB + i) = u;
    } else if (t < A + B) {
        const int idx = (int)(t - A);
        const int row = idx / 768, d = idx - row * 768;
        const int s = row & 2047;
        const float e = pa.emb[(long)pa.ids[row] * 768 + d];
        const int j = d >> 1;
        const float ang = (float)s * __expf(-0.011992630692677324f * (float)(4 * j));
        const float pe = (d & 1) ? __cosf(ang) : __sinf(ang);
        const float v = e + pe;
        pa.xf[idx] = v;
        pa.xb[idx] = f2bf(v);
    } else {
        const int i = (int)(t - A - B);
        if (i < 4608) {
            int l = i / 2304, j = i - l * 2304;
            float v = (j < 768) ? pa.bq[l * 768 + j]
                    : (j < 1536) ? pa.bk[l * 768 + j - 768]
                    : pa.bv[l * 768 + j - 1536];
            pa.bqkv[i] = v;
        }
    }
}

// ---------------------------------------------------------------------------
extern "C" void kernel_launch(void* const* d_in, const int* in_sizes, int n_in,
                              void* d_out, int out_size, void* d_ws, size_t ws_size,
                              hipStream_t stream)
{
    const int S = 2048, D = 768, H = 12, L = 2, V = 32000, DF = 3072, M = 4096, NQKV = 2304;
    (void)in_sizes; (void)n_in; (void)out_size; (void)ws_size; (void)H; (void)S;

    const int*   ids  = (const int*)  d_in[0];
    const float* emb  = (const float*)d_in[1];
    const float* Wq   = (const float*)d_in[2];
    const float* bq   = (const float*)d_in[3];
    const float* Wk   = (const float*)d_in[4];
    const float* bk   = (const float*)d_in[5];
    const float* Wv   = (const float*)d_in[6];
    const float* bv   = (const float*)d_in[7];
    const float* Wo   = (const float*)d_in[8];
    const float* bo   = (const float*)d_in[9];
    const float* ln1g = (const float*)d_in[10];
    const float* ln1b = (const float*)d_in[11];
    const float* W1   = (const float*)d_in[12];
    const float* b1   = (const float*)d_in[13];
    const float* W2   = (const float*)d_in[14];
    const float* b2   = (const float*)d_in[15];
    const float* ln2g = (const float*)d_in[16];
    const float* ln2b = (const float*)d_in[17];
    const float* Wd   = (const float*)d_in[18];
    const float* bd   = (const float*)d_in[19];
    const float* lnmg = (const float*)d_in[20];
    const float* lnmb = (const float*)d_in[21];
    const float* decb = (const float*)d_in[22];

    char* p = (char*)d_ws;
    auto carve = [&](size_t bytes) { char* r = p; p += (bytes + 255) & ~(size_t)255; return r; };
    u16*   embB  = (u16*)  carve((size_t)V * D * 2);
    u16*   wqkvT = (u16*)  carve((size_t)L * NQKV * D * 2);
    float* bqkv  = (float*)carve((size_t)L * NQKV * 4);
    u16*   woT   = (u16*)  carve((size_t)L * D * D * 2);
    u16*   w1T   = (u16*)  carve((size_t)L * DF * D * 2);
    u16*   w2T   = (u16*)  carve((size_t)L * D * DF * 2);
    u16*   wdT   = (u16*)  carve((size_t)D * D * 2);
    float* xf    = (float*)carve((size_t)M * D * 4);
    u16*   xb    = (u16*)  carve((size_t)M * D * 2);
    u16*   qkvB  = (u16*)  carve((size_t)M * NQKV * 2);
    u16*   aoB   = (u16*)  carve((size_t)M * D * 2);
    float* tmpf  = (float*)carve((size_t)M * D * 4 * 4);   // split-K partials
    u16*   hB    = (u16*)  carve((size_t)M * DF * 2);

    {   // single prep launch: 13 transposes + cvt + embed/PE + bias concat
        PrepArgs pa;
        for (int l = 0; l < L; ++l) {
            pa.tsrc[l * 4 + 0] = Wq + (size_t)l * D * D; pa.tdst[l * 4 + 0] = wqkvT + (size_t)l * NQKV * D;
            pa.tsrc[l * 4 + 1] = Wk + (size_t)l * D * D; pa.tdst[l * 4 + 1] = wqkvT + (size_t)l * NQKV * D + (size_t)D * D;
            pa.tsrc[l * 4 + 2] = Wv + (size_t)l * D * D; pa.tdst[l * 4 + 2] = wqkvT + (size_t)l * NQKV * D + (size_t)2 * D * D;
            pa.tsrc[l * 4 + 3] = Wo + (size_t)l * D * D; pa.tdst[l * 4 + 3] = woT + (size_t)l * D * D;
        }
        pa.tsrc[8]  = Wd;                    pa.tdst[8]  = wdT;
        pa.tsrc[9]  = W1;                    pa.tdst[9]  = w1T;
        pa.tsrc[10] = W1 + (size_t)D * DF;   pa.tdst[10] = w1T + (size_t)DF * D;
        pa.tsrc[11] = W2;                    pa.tdst[11] = w2T;
        pa.tsrc[12] = W2 + (size_t)DF * D;   pa.tdst[12] = w2T + (size_t)D * DF;
        pa.emb = emb; pa.embB = embB;
        pa.ids = ids; pa.xf = xf; pa.xb = xb;
        pa.bq = bq; pa.bk = bk; pa.bv = bv; pa.bqkv = bqkv;
        prep_all<<<14400 + 36306, 256, 0, stream>>>(pa);
    }

    // q pre-scale: 1/sqrt(768) * log2(e)  (attention uses exp2)
    const float qscale = 0.036084391824351615f * 1.4426950408889634f;
    const long PSTR = (long)M * D;
    for (int l = 0; l < L; ++l) {
        gemm_bf16<0, 0, 0, 1, 1><<<dim3(NQKV / 128, M / 128), 256, 0, stream>>>(xb, wqkvT + (size_t)l * NQKV * D, bqkv + l * NQKV, qkvB, NQKV, D, qscale);
        attn_fwd<<<dim3(24, 32), 256, 0, stream>>>(qkvB, aoB);
        gemm64<0, 1><<<dim3(D / 64, M / 64), 256, 0, stream>>>(aoB, woT + (size_t)l * D * D, bo + l * D, tmpf, D, D);
        ln_fused<1><<<M / 4, 256, 0, stream>>>(xf, tmpf, PSTR, ln1g + l * D, ln1b + l * D, xf, xb);
        gemm_bf16<1, 0, 0, 1, 0><<<dim3(DF / 128, M / 128), 256, 0, stream>>>(xb, w1T + (size_t)l * DF * D, b1 + l * DF, hB, DF, D, 1.0f);
        gemm_bf16<0, 1, 0, 2, 0><<<dim3(D / 128, M / 128, 2), 256, 0, stream>>>(hB, w2T + (size_t)l * D * DF, b2 + l * D, tmpf, D, DF, 1.0f);
        ln_fused<2><<<M / 4, 256, 0, stream>>>(xf, tmpf, PSTR, ln2g + l * D, ln2b + l * D, xf, xb);
    }
    gemm64<1, 1><<<dim3(D / 64, M / 64), 256, 0, stream>>>(xb, wdT, bd, tmpf, D, D);
    ln_fused<0><<<M / 4, 256, 0, stream>>>(tmpf, nullptr, 0, lnmg, lnmb, nullptr, aoB);
    gemm_bf16<0, 1, 1, 1, 0><<<V / 128 * 32, 256, 0, stream>>>(aoB, embB, decb, (float*)d_out, V, D, 1.0f);
}